// Round 1
// 2570.590 us; speedup vs baseline: 1.1291x; 1.1291x over previous
//
#include <hip/hip_runtime.h>

// Problem constants
#define BB 4
#define SS 4096
#define DD 2048
#define NHEAD 16
#define HDIM 128
#define MM (BB * SS)   // 16384 rows

typedef _Float16 f16;
typedef __attribute__((ext_vector_type(8))) _Float16 half8;
typedef __attribute__((ext_vector_type(4))) _Float16 half4;
typedef __attribute__((ext_vector_type(4))) float floatx4;

typedef __attribute__((address_space(3))) char lds_char;
typedef const __attribute__((address_space(1))) char glb_char;

__device__ __forceinline__ void async_copy16(const void* g, void* l) {
    // global -> LDS direct copy, 16B per lane; LDS dest = wave-uniform base + lane*16
    __builtin_amdgcn_global_load_lds((glb_char*)g, (lds_char*)l, 16, 0, 0);
}

// ---------------- cast fp32 -> fp16 (vectorized) ----------------
__global__ __launch_bounds__(256) void cast_f32_f16_kernel(
    const float* __restrict__ src, f16* __restrict__ dst, int n4) {
    int i = blockIdx.x * blockDim.x + threadIdx.x;
    if (i < n4) {
        float4 v = ((const float4*)src)[i];
        half4 h;
        h[0] = (f16)v.x; h[1] = (f16)v.y; h[2] = (f16)v.z; h[3] = (f16)v.w;
        ((half4*)dst)[i] = h;
    }
}

// ---------------- transpose + cast: dst[e][d] = src[d][e] ----------------
__global__ __launch_bounds__(256) void transpose_cast_kernel(
    const float* __restrict__ src, f16* __restrict__ dst, int dim) {
    __shared__ float tile[32][33];   // +1 pad: conflict-free transpose
    int tx = threadIdx.x & 31, ty = threadIdx.x >> 5;  // 32 x 8
    int bx = blockIdx.x * 32, by = blockIdx.y * 32;
#pragma unroll
    for (int r = 0; r < 4; ++r)
        tile[ty + 8 * r][tx] = src[(size_t)(by + ty + 8 * r) * dim + bx + tx];
    __syncthreads();
#pragma unroll
    for (int r = 0; r < 4; ++r)
        dst[(size_t)(bx + ty + 8 * r) * dim + by + tx] = (f16)tile[tx][ty + 8 * r];
}

// ---------------- fp16 MFMA GEMM: C[M,N] = A[M,K] @ Bt[N,K]^T ----------------
// 128x128 tile, BK=32, 256 threads = 4 waves in 2x2, each wave 64x64 (4x4 frags of 16x16x32)
// MODE 0: out fp16 with fp32 bias (input projection -> x buffer)
// MODE 1: out fp32, no bias (output projection -> d_out)
template <int MODE>
__global__ __launch_bounds__(256) void gemm_f16_kernel(
    const f16* __restrict__ A, const f16* __restrict__ Bt,
    const float* __restrict__ bias, f16* __restrict__ outH,
    float* __restrict__ outF, int M, int N, int K) {
    __shared__ __align__(16) char smem[16384];   // As 8KB | Bs 8KB
    f16* As = (f16*)smem;
    f16* Bs = (f16*)(smem + 8192);

    const int tid = threadIdx.x;
    const int lane = tid & 63;
    const int wave = tid >> 6;
    const int wm = wave >> 1, wn = wave & 1;
    const int lm = lane & 15, quad = lane >> 4;
    const int m0 = blockIdx.y * 128, n0 = blockIdx.x * 128;

    floatx4 acc[4][4];
#pragma unroll
    for (int i = 0; i < 4; ++i)
#pragma unroll
        for (int j = 0; j < 4; ++j)
#pragma unroll
            for (int r = 0; r < 4; ++r) acc[i][j][r] = 0.f;

    // staging map: thread t loads 16B: row = t>>2 (+64 for round 1), k-elem = (t&3)*8
    const int srow = tid >> 2;
    const int skk = (tid & 3) * 8;
    const int wbase = (tid >> 6) * 1024;  // wave-uniform LDS byte base
    const f16* Ag = A + (size_t)(m0 + srow) * K + skk;
    const f16* Bg = Bt + (size_t)(n0 + srow) * K + skk;

    for (int kb = 0; kb < K; kb += 32) {
        async_copy16(Ag + kb, smem + 0 + wbase);
        async_copy16(Ag + (size_t)64 * K + kb, smem + 4096 + wbase);
        async_copy16(Bg + kb, smem + 8192 + wbase);
        async_copy16(Bg + (size_t)64 * K + kb, smem + 12288 + wbase);
        asm volatile("s_waitcnt vmcnt(0)" ::: "memory");
        __syncthreads();

        half8 af[4], bf[4];
#pragma unroll
        for (int i = 0; i < 4; ++i)
            af[i] = *(const half8*)(As + (wm * 64 + i * 16 + lm) * 32 + quad * 8);
#pragma unroll
        for (int j = 0; j < 4; ++j)
            bf[j] = *(const half8*)(Bs + (wn * 64 + j * 16 + lm) * 32 + quad * 8);
#pragma unroll
        for (int i = 0; i < 4; ++i)
#pragma unroll
            for (int j = 0; j < 4; ++j)
                acc[i][j] = __builtin_amdgcn_mfma_f32_16x16x32_f16(af[i], bf[j], acc[i][j], 0, 0, 0);
        __syncthreads();
    }

    // epilogue: C/D layout col = lane&15, row = quad*4 + r
#pragma unroll
    for (int j = 0; j < 4; ++j) {
        int col = n0 + wn * 64 + j * 16 + lm;
        float bj = (MODE == 0) ? bias[col] : 0.f;
#pragma unroll
        for (int i = 0; i < 4; ++i) {
            int row0 = m0 + wm * 64 + i * 16 + quad * 4;
#pragma unroll
            for (int r = 0; r < 4; ++r) {
                float v = acc[i][j][r] + bj;
                if (MODE == 0) outH[(size_t)(row0 + r) * N + col] = (f16)v;
                else           outF[(size_t)(row0 + r) * N + col] = v;
            }
        }
    }
}

// ---------------- sequential scan: one workgroup per (b, n) ----------------
// 256 threads = 4 waves. Wave w owns output cols [32w, 32w+32).
// Lane (cl = lane&31, jh = lane>>5): col c = 32w+cl, j-range [64*jh, 64*jh+64).
// W column slice in VGPRs (64 floats). Per step:
//   64 FMAs (4 indep chains) -> shfl_xor(32) reduce -> tanh -> LDS h write
//   ONE raw s_barrier per step (lgkmcnt only; never drains vmcnt).
// h double-buffered in LDS (read buf != write buf -> single barrier is safe).
// x staged 16 timesteps at a time via global_load_lds (issued one group = 16
// steps ahead); y staged in LDS, flushed 4KB-coalesced once per group.
__global__ __launch_bounds__(256) void scan_kernel(
    const f16* __restrict__ xb, const float* __restrict__ state_weight,
    const float* __restrict__ input_state, f16* __restrict__ yb) {
    const int b = blockIdx.x >> 4;
    const int n = blockIdx.x & 15;
    const int tid = threadIdx.x;
    const int lane = tid & 63;
    const int wave = tid >> 6;
    const int cl = lane & 31;
    const int c = wave * 32 + cl;          // output col 0..127
    const int jh = lane >> 5;              // which half of j
    const int jb = jh * 68;                // padded base into h row (64 + 4 pad)
    const int cpad = c + ((c >> 6) << 2);  // padded write index

    __shared__ __align__(16) float hsb[2][136];       // h double buffer (+4 pad between halves)
    __shared__ __align__(16) f16 xsb[2][16][128];     // x staging, 2 x 4KB
    __shared__ __align__(16) f16 ysb[2][16][128];     // y staging, 2 x 4KB

    // W column slice into regs: wreg[i] = W[jh*64 + i][c]
    float wreg[64];
    {
        const float* Wc = state_weight + (size_t)n * HDIM * HDIM + (size_t)(jh * 64) * HDIM + c;
#pragma unroll
        for (int i = 0; i < 64; ++i) wreg[i] = Wc[(size_t)i * HDIM];
    }

    if (tid < 128)
        hsb[0][tid + ((tid >> 6) << 2)] = input_state[((size_t)b * NHEAD + n) * HDIM + tid];

    const f16* xrow = xb + (size_t)b * SS * DD + n * HDIM;
    f16* yrow = yb + (size_t)b * SS * DD + n * HDIM;

    // group staging map: thread tid covers t' = tid>>4 (16 steps), cols (tid&15)*8..+8
    const int tq = tid >> 4;
    const int c8 = (tid & 15) * 8;

    // prologue: stage group 0's x
    async_copy16(xrow + (size_t)tq * DD + c8, (char*)(&xsb[0][0][0]) + wave * 1024);
    asm volatile("s_waitcnt vmcnt(0)" ::: "memory");
    __syncthreads();

    int buf = 0;
    for (int g = 0; g < SS / 16; ++g) {
        const int tg = g << 4;
        // issue next group's x copy (consumed 16 steps from now)
        if (g + 1 < SS / 16)
            async_copy16(xrow + (size_t)(tg + 16 + tq) * DD + c8,
                         (char*)(&xsb[buf ^ 1][0][0]) + wave * 1024);

        // 16 recurrent steps; h ping-pongs 0->1->0->... (16 is even: parity stable)
#pragma unroll 1
        for (int uu = 0; uu < 8; ++uu) {
#pragma unroll
            for (int par = 0; par < 2; ++par) {
                const int u = uu * 2 + par;
                const float* hr = hsb[par];        // static index (unrolled)
                float* hw = hsb[par ^ 1];
                float xval = (float)xsb[buf][u][c];
                float a0 = 0.f, a1 = 0.f, a2 = 0.f, a3 = 0.f;
#pragma unroll
                for (int q = 0; q < 16; ++q) {
                    float4 h4 = *(const float4*)&hr[jb + 4 * q];   // broadcast read
                    a0 += h4.x * wreg[4 * q + 0];
                    a1 += h4.y * wreg[4 * q + 1];
                    a2 += h4.z * wreg[4 * q + 2];
                    a3 += h4.w * wreg[4 * q + 3];
                }
                float v = (a0 + a1) + (a2 + a3);
                v += __shfl_xor(v, 32);            // partner j-half, same col
                v += xval;
                float ex = exp2f(v * 2.8853900817779268f);   // exp(2v)
                float ns = 1.f - 2.f * __builtin_amdgcn_rcpf(ex + 1.f);
                if (lane < 32) hw[cpad] = ns;                 // h for next step
                else           ysb[buf][u][c] = (f16)ns;      // y staging
                asm volatile("s_waitcnt lgkmcnt(0)" ::: "memory");
                __builtin_amdgcn_s_barrier();       // raw barrier: no vmcnt drain
            }
        }

        // group boundary: next-x copy was issued 16 steps ago -> wait is ~free.
        // (also drains last group's flush store, equally old)
        asm volatile("s_waitcnt vmcnt(0)" ::: "memory");
        // flush this group's y: 4KB coalesced (16B/thread)
        half8 yv = *(const half8*)&ysb[buf][tq][c8];
        *(half8*)(yrow + (size_t)(tg + tq) * DD + c8) = yv;
        __builtin_amdgcn_s_barrier();               // all waves' copies complete
        buf ^= 1;
    }
}

// ---------------- launch ----------------
extern "C" void kernel_launch(void* const* d_in, const int* in_sizes, int n_in,
                              void* d_out, int out_size, void* d_ws, size_t ws_size,
                              hipStream_t stream) {
    const float* input       = (const float*)d_in[0];
    const float* input_state = (const float*)d_in[1];
    const float* w_in        = (const float*)d_in[2];
    const float* b_in        = (const float*)d_in[3];
    const float* state_w     = (const float*)d_in[4];
    const float* w_out       = (const float*)d_in[5];
    float* out = (float*)d_out;

    // workspace layout (144 MB total):
    //   [0, 64MB)      Ab  : input cast to f16   (reused as yb after GEMM1)
    //   [64, 72MB)     W1b : w_in^T  f16
    //   [72, 80MB)     W2b : w_out^T f16
    //   [80, 144MB)    xb  : projected input, f16
    char* ws = (char*)d_ws;
    f16* Ab  = (f16*)ws;
    f16* W1b = (f16*)(ws + 67108864);
    f16* W2b = (f16*)(ws + 75497472);
    f16* xb  = (f16*)(ws + 83886080);
    f16* yb  = Ab;  // alias: Ab is dead after GEMM1

    cast_f32_f16_kernel<<<(MM * DD / 4 + 255) / 256, 256, 0, stream>>>(input, Ab, MM * DD / 4);

    dim3 tg(DD / 32, DD / 32);
    transpose_cast_kernel<<<tg, 256, 0, stream>>>(w_in, W1b, DD);
    transpose_cast_kernel<<<tg, 256, 0, stream>>>(w_out, W2b, DD);

    dim3 gg(DD / 128, MM / 128);
    gemm_f16_kernel<0><<<gg, 256, 0, stream>>>(Ab, W1b, b_in, xb, nullptr, MM, DD, DD);

    scan_kernel<<<BB * NHEAD, 256, 0, stream>>>(xb, state_w, input_state, yb);

    gemm_f16_kernel<1><<<gg, 256, 0, stream>>>(yb, W2b, nullptr, nullptr, out, MM, DD, DD);
}

// Round 3
// 2381.045 us; speedup vs baseline: 1.2189x; 1.0796x over previous
//
#include <hip/hip_runtime.h>

// Problem constants
#define BB 4
#define SS 4096
#define DD 2048
#define NHEAD 16
#define HDIM 128
#define MM (BB * SS)   // 16384 rows

typedef _Float16 f16;
typedef __attribute__((ext_vector_type(8))) _Float16 half8;
typedef __attribute__((ext_vector_type(4))) _Float16 half4;
typedef __attribute__((ext_vector_type(4))) float floatx4;

typedef __attribute__((address_space(3))) char lds_char;
typedef const __attribute__((address_space(1))) char glb_char;

__device__ __forceinline__ void async_copy16(const void* g, void* l) {
    // global -> LDS direct copy, 16B per lane; LDS dest = wave-uniform base + lane*16
    __builtin_amdgcn_global_load_lds((glb_char*)g, (lds_char*)l, 16, 0, 0);
}

// ---------------- cast fp32 -> fp16 (vectorized) ----------------
__global__ __launch_bounds__(256) void cast_f32_f16_kernel(
    const float* __restrict__ src, f16* __restrict__ dst, int n4) {
    int i = blockIdx.x * blockDim.x + threadIdx.x;
    if (i < n4) {
        float4 v = ((const float4*)src)[i];
        half4 h;
        h[0] = (f16)v.x; h[1] = (f16)v.y; h[2] = (f16)v.z; h[3] = (f16)v.w;
        ((half4*)dst)[i] = h;
    }
}

// ---------------- transpose + cast: dst[e][d] = src[d][e] ----------------
__global__ __launch_bounds__(256) void transpose_cast_kernel(
    const float* __restrict__ src, f16* __restrict__ dst, int dim) {
    __shared__ float tile[32][33];   // +1 pad: conflict-free transpose
    int tx = threadIdx.x & 31, ty = threadIdx.x >> 5;  // 32 x 8
    int bx = blockIdx.x * 32, by = blockIdx.y * 32;
#pragma unroll
    for (int r = 0; r < 4; ++r)
        tile[ty + 8 * r][tx] = src[(size_t)(by + ty + 8 * r) * dim + bx + tx];
    __syncthreads();
#pragma unroll
    for (int r = 0; r < 4; ++r)
        dst[(size_t)(bx + ty + 8 * r) * dim + by + tx] = (f16)tile[tx][ty + 8 * r];
}

// ---------------- fp16 MFMA GEMM: C[M,N] = A[M,K] @ Bt[N,K]^T ----------------
// 128x128 tile, BK=32, 256 threads = 4 waves in 2x2, each wave 64x64 (4x4 frags of 16x16x32)
// MODE 0: out fp16 with fp32 bias (input projection -> x buffer)
// MODE 1: out fp32, no bias (output projection -> d_out)
template <int MODE>
__global__ __launch_bounds__(256) void gemm_f16_kernel(
    const f16* __restrict__ A, const f16* __restrict__ Bt,
    const float* __restrict__ bias, f16* __restrict__ outH,
    float* __restrict__ outF, int M, int N, int K) {
    __shared__ __align__(16) char smem[16384];   // As 8KB | Bs 8KB
    f16* As = (f16*)smem;
    f16* Bs = (f16*)(smem + 8192);

    const int tid = threadIdx.x;
    const int lane = tid & 63;
    const int wave = tid >> 6;
    const int wm = wave >> 1, wn = wave & 1;
    const int lm = lane & 15, quad = lane >> 4;
    const int m0 = blockIdx.y * 128, n0 = blockIdx.x * 128;

    floatx4 acc[4][4];
#pragma unroll
    for (int i = 0; i < 4; ++i)
#pragma unroll
        for (int j = 0; j < 4; ++j)
#pragma unroll
            for (int r = 0; r < 4; ++r) acc[i][j][r] = 0.f;

    const int srow = tid >> 2;
    const int skk = (tid & 3) * 8;
    const int wbase = (tid >> 6) * 1024;  // wave-uniform LDS byte base
    const f16* Ag = A + (size_t)(m0 + srow) * K + skk;
    const f16* Bg = Bt + (size_t)(n0 + srow) * K + skk;

    for (int kb = 0; kb < K; kb += 32) {
        async_copy16(Ag + kb, smem + 0 + wbase);
        async_copy16(Ag + (size_t)64 * K + kb, smem + 4096 + wbase);
        async_copy16(Bg + kb, smem + 8192 + wbase);
        async_copy16(Bg + (size_t)64 * K + kb, smem + 12288 + wbase);
        asm volatile("s_waitcnt vmcnt(0)" ::: "memory");
        __syncthreads();

        half8 af[4], bf[4];
#pragma unroll
        for (int i = 0; i < 4; ++i)
            af[i] = *(const half8*)(As + (wm * 64 + i * 16 + lm) * 32 + quad * 8);
#pragma unroll
        for (int j = 0; j < 4; ++j)
            bf[j] = *(const half8*)(Bs + (wn * 64 + j * 16 + lm) * 32 + quad * 8);
#pragma unroll
        for (int i = 0; i < 4; ++i)
#pragma unroll
            for (int j = 0; j < 4; ++j)
                acc[i][j] = __builtin_amdgcn_mfma_f32_16x16x32_f16(af[i], bf[j], acc[i][j], 0, 0, 0);
        __syncthreads();
    }

#pragma unroll
    for (int j = 0; j < 4; ++j) {
        int col = n0 + wn * 64 + j * 16 + lm;
        float bj = (MODE == 0) ? bias[col] : 0.f;
#pragma unroll
        for (int i = 0; i < 4; ++i) {
            int row0 = m0 + wm * 64 + i * 16 + quad * 4;
#pragma unroll
            for (int r = 0; r < 4; ++r) {
                float v = acc[i][j][r] + bj;
                if (MODE == 0) outH[(size_t)(row0 + r) * N + col] = (f16)v;
                else           outF[(size_t)(row0 + r) * N + col] = v;
            }
        }
    }
}

// ---------------- sequential scan via MFMA: one workgroup per head n ----------------
// C(out-dims x batch) = W^T(A, regs) * h(B, LDS).  4 waves, wave w owns out-dims
// [32w,32w+32) as 2 rowtiles of 16.  Batches are MFMA columns (4 of 16 used; cols
// 4-15 duplicate batch col&3 -> finite garbage, masked on write).
// Per step/wave: 4 ds_read_b128 (h B-frags) + 2 b64 x reads + 8 MFMA + tanh +
// 2 masked b64 h writes + 2 masked b64 y writes; ONE raw s_barrier (lgkm only).
// h double-buffered in LDS (2.5KB).  x staged per 16-step group via global_load_lds
// with lane->(b,c)-interleaved chunks (conflict-free b64 reads); y staged in LDS,
// flushed coalesced per group.  vmcnt(8) counted waits only per group.

// h LDS byte offset: batch b (0..3), element k (0..127).  Padded-linear (stride 320B):
// b128 reads: chunk index (b*20 + quad) mod 8 -> {0..3} for b in {0,2}, {4..7} for
// b in {1,3} => 2-way bank aliasing, which is free on CDNA4.  BIJECTIVE (the R2
// additive swizzle collided chunks: m + ((m+b)&3) is not injective -> absmax 1.2).
__device__ __forceinline__ int h_off(int b, int k) {
    return b * 320 + k * 2;
}

__global__ __launch_bounds__(256) void scan_kernel(
    const f16* __restrict__ xb, const float* __restrict__ state_weight,
    const float* __restrict__ input_state, f16* __restrict__ yb) {
    const int n = blockIdx.x;          // head
    const int tid = threadIdx.x;
    const int lane = tid & 63;
    const int w = tid >> 6;
    const int lm = lane & 15;          // A row within tile / C col (batch)
    const int quad = lane >> 4;
    const int bb = lane & 3;           // clamped batch for reads (real for lm<4)

    __shared__ __align__(16) char hsb[2][4 * 320];      // 2.5 KB h ping-pong
    __shared__ __align__(16) char xsb[2][16 * 1024];    // 32 KB x staging
    __shared__ __align__(16) char ysb[16 * 1088];       // 17 KB y staging

    // ---- W A-frags: wfrag[rt][kt][j] = W[n][h = kt*32+quad*8+j][p = (w*2+rt)*16+lm]
    half8 wfrag[2][4];
    {
        const float* Wn = state_weight + (size_t)n * HDIM * HDIM;
#pragma unroll
        for (int rt = 0; rt < 2; ++rt) {
            const int row = (w * 2 + rt) * 16 + lm;
#pragma unroll
            for (int kt = 0; kt < 4; ++kt) {
                half8 f;
#pragma unroll
                for (int j = 0; j < 8; ++j)
                    f[j] = (f16)Wn[(size_t)(kt * 32 + quad * 8 + j) * HDIM + row];
                wfrag[rt][kt] = f;
            }
        }
    }

    // ---- init h0
    for (int idx = tid; idx < 512; idx += 256) {
        int b = idx >> 7, k = idx & 127;
        *(f16*)&hsb[0][h_off(b, k)] =
            (f16)input_state[((size_t)b * NHEAD + n) * HDIM + k];
    }

    const f16* xg = xb + (size_t)n * HDIM;   // + (b*SS + t)*DD + c
    f16* yg = yb + (size_t)n * HDIM;

    // ---- prologue: stage group 0 x.  Chunk layout within u-row: pos(b,c8) = (c8block*4+b)*16
    // lane l fetches (b = l&3, c8 = (l>>2)*8) so LDS lands lane-linear in that layout.
#pragma unroll
    for (int i = 0; i < 4; ++i) {
        int u = i * 4 + w;
        async_copy16(xg + ((size_t)bb * SS + u) * DD + (lane >> 2) * 8,
                     &xsb[0][u * 1024]);
    }
    asm volatile("s_waitcnt vmcnt(0)" ::: "memory");
    __syncthreads();

    const int kp0 = (w * 2 + 0) * 16 + quad * 4;   // out-dim base, rowtile 0
    const int kp1 = (w * 2 + 1) * 16 + quad * 4;   // out-dim base, rowtile 1
    const int xo0 = (((kp0 >> 3) * 4 + bb) << 4) + ((kp0 & 7) * 2);
    const int xo1 = (((kp1 >> 3) * 4 + bb) << 4) + ((kp1 & 7) * 2);

    int buf = 0;
    for (int g = 0; g < SS / 16; ++g) {
        const int tg = g * 16;
        if (g + 1 < SS / 16) {
#pragma unroll
            for (int i = 0; i < 4; ++i) {
                int u = i * 4 + w;
                async_copy16(xg + ((size_t)bb * SS + (tg + 16 + u)) * DD + (lane >> 2) * 8,
                             &xsb[buf ^ 1][u * 1024]);
            }
        }
        // newest 8 vm ops = {4 flush stores of g-1, 4 copies for g+1}; anything older
        // (this group's copies) is forced complete.  Never vmcnt(0) in the loop.
        asm volatile("s_waitcnt vmcnt(8)" ::: "memory");

#pragma unroll 1
        for (int uu = 0; uu < 8; ++uu) {
#pragma unroll
            for (int par = 0; par < 2; ++par) {
                const int u = uu * 2 + par;
                const char* hr = hsb[par];           // static after unroll
                char* hw2 = hsb[par ^ 1];
                const char* xu = &xsb[buf][u * 1024];

                half4 xa = *(const half4*)(xu + xo0);
                half4 xc = *(const half4*)(xu + xo1);

                half8 hf0 = *(const half8*)(hr + h_off(bb, 0 * 32 + quad * 8));
                half8 hf1 = *(const half8*)(hr + h_off(bb, 1 * 32 + quad * 8));
                half8 hf2 = *(const half8*)(hr + h_off(bb, 2 * 32 + quad * 8));
                half8 hf3 = *(const half8*)(hr + h_off(bb, 3 * 32 + quad * 8));

                floatx4 c0, c1;
                c0[0] = (float)xa[0]; c0[1] = (float)xa[1];
                c0[2] = (float)xa[2]; c0[3] = (float)xa[3];
                c1[0] = (float)xc[0]; c1[1] = (float)xc[1];
                c1[2] = (float)xc[2]; c1[3] = (float)xc[3];

                c0 = __builtin_amdgcn_mfma_f32_16x16x32_f16(wfrag[0][0], hf0, c0, 0, 0, 0);
                c1 = __builtin_amdgcn_mfma_f32_16x16x32_f16(wfrag[1][0], hf0, c1, 0, 0, 0);
                c0 = __builtin_amdgcn_mfma_f32_16x16x32_f16(wfrag[0][1], hf1, c0, 0, 0, 0);
                c1 = __builtin_amdgcn_mfma_f32_16x16x32_f16(wfrag[1][1], hf1, c1, 0, 0, 0);
                c0 = __builtin_amdgcn_mfma_f32_16x16x32_f16(wfrag[0][2], hf2, c0, 0, 0, 0);
                c1 = __builtin_amdgcn_mfma_f32_16x16x32_f16(wfrag[1][2], hf2, c1, 0, 0, 0);
                c0 = __builtin_amdgcn_mfma_f32_16x16x32_f16(wfrag[0][3], hf3, c0, 0, 0, 0);
                c1 = __builtin_amdgcn_mfma_f32_16x16x32_f16(wfrag[1][3], hf3, c1, 0, 0, 0);

                // tanh(v) = 1 - 2/(exp(2v)+1)
                half4 h0, h1;
#pragma unroll
                for (int r = 0; r < 4; ++r) {
                    float ex = __expf(2.f * c0[r]);
                    h0[r] = (f16)(1.f - 2.f * __builtin_amdgcn_rcpf(ex + 1.f));
                }
#pragma unroll
                for (int r = 0; r < 4; ++r) {
                    float ex = __expf(2.f * c1[r]);
                    h1[r] = (f16)(1.f - 2.f * __builtin_amdgcn_rcpf(ex + 1.f));
                }

                if (lm < 4) {   // real batch columns only
                    *(half4*)(hw2 + h_off(lm, kp0)) = h0;
                    *(half4*)(hw2 + h_off(lm, kp1)) = h1;
                    *(half4*)&ysb[u * 1088 + lm * 272 + kp0 * 2] = h0;
                    *(half4*)&ysb[u * 1088 + lm * 272 + kp1 * 2] = h1;
                }
                asm volatile("s_waitcnt lgkmcnt(0)" ::: "memory");
                __builtin_amdgcn_s_barrier();       // raw: no vmcnt drain
            }
        }

        // ---- flush this group's y, coalesced (256B per (u,b) segment)
#pragma unroll
        for (int i = 0; i < 4; ++i) {
            int u = i * 4 + w;
            int b = quad;                 // lane>>4
            int c8 = lm * 8;
            half8 yv = *(const half8*)&ysb[u * 1088 + b * 272 + c8 * 2];
            *(half8*)(yg + ((size_t)b * SS + tg + u) * DD + c8) = yv;
        }
        __builtin_amdgcn_s_barrier();     // protect ysb reuse by next group
        buf ^= 1;
    }
}

// ---------------- launch ----------------
extern "C" void kernel_launch(void* const* d_in, const int* in_sizes, int n_in,
                              void* d_out, int out_size, void* d_ws, size_t ws_size,
                              hipStream_t stream) {
    const float* input       = (const float*)d_in[0];
    const float* input_state = (const float*)d_in[1];
    const float* w_in        = (const float*)d_in[2];
    const float* b_in        = (const float*)d_in[3];
    const float* state_w     = (const float*)d_in[4];
    const float* w_out       = (const float*)d_in[5];
    float* out = (float*)d_out;

    // workspace layout (144 MB total):
    //   [0, 64MB)      Ab  : input cast to f16   (reused as yb after GEMM1)
    //   [64, 72MB)     W1b : w_in^T  f16
    //   [72, 80MB)     W2b : w_out^T f16
    //   [80, 144MB)    xb  : projected input, f16
    char* ws = (char*)d_ws;
    f16* Ab  = (f16*)ws;
    f16* W1b = (f16*)(ws + 67108864);
    f16* W2b = (f16*)(ws + 75497472);
    f16* xb  = (f16*)(ws + 83886080);
    f16* yb  = Ab;  // alias: Ab is dead after GEMM1

    cast_f32_f16_kernel<<<(MM * DD / 4 + 255) / 256, 256, 0, stream>>>(input, Ab, MM * DD / 4);

    dim3 tg(DD / 32, DD / 32);
    transpose_cast_kernel<<<tg, 256, 0, stream>>>(w_in, W1b, DD);
    transpose_cast_kernel<<<tg, 256, 0, stream>>>(w_out, W2b, DD);

    dim3 gg(DD / 128, MM / 128);
    gemm_f16_kernel<0><<<gg, 256, 0, stream>>>(Ab, W1b, b_in, xb, nullptr, MM, DD, DD);

    scan_kernel<<<NHEAD, 256, 0, stream>>>(xb, state_w, input_state, yb);

    gemm_f16_kernel<1><<<gg, 256, 0, stream>>>(yb, W2b, nullptr, nullptr, out, MM, DD, DD);
}